// Round 3
// baseline (615.224 us; speedup 1.0000x reference)
//
#include <hip/hip_runtime.h>
#include <hip/hip_bf16.h>
#include <math.h>

#define NN 16384     // nodes
#define NE 262144    // edges
#define KDIM1 480
#define DHID 256
#define DOUT3 128
#define NG 256       // graphs

// ============================ CSR build ============================

__global__ __launch_bounds__(256) void k_edge_count(const int* __restrict__ ei,
                                                    const float* __restrict__ ea,
                                                    int* __restrict__ deg,
                                                    float* __restrict__ easum) {
  int e = blockIdx.x * 256 + threadIdx.x;
  if (e >= NE) return;
  int d = ei[NE + e];
  atomicAdd(&deg[d], 1);
  atomicAdd(&easum[d], ea[e]);
}

__global__ __launch_bounds__(1024) void k_scan(const int* __restrict__ deg,
                                               float* __restrict__ easum,
                                               int* __restrict__ offs,
                                               int* __restrict__ cursor) {
  __shared__ int sums[1024];
  int t = threadIdx.x;
  int base = t * 16;
  int local[16];
  int s = 0;
#pragma unroll
  for (int i = 0; i < 16; ++i) { local[i] = deg[base + i]; s += local[i]; }
  sums[t] = s;
  __syncthreads();
  for (int d = 1; d < 1024; d <<= 1) {
    int v = (t >= d) ? sums[t - d] : 0;
    __syncthreads();
    sums[t] += v;
    __syncthreads();
  }
  int prefix = (t == 0) ? 0 : sums[t - 1];
#pragma unroll
  for (int i = 0; i < 16; ++i) {
    offs[base + i] = prefix;
    cursor[base + i] = prefix;
    prefix += local[i];
  }
  if (t == 1023) offs[NN] = prefix;
#pragma unroll
  for (int i = 0; i < 16; ++i) {
    easum[base + i] = easum[base + i] / fmaxf((float)local[i], 1.f);
  }
}

__global__ __launch_bounds__(256) void k_fill_csr(const int* __restrict__ ei,
                                                  const float* __restrict__ ea,
                                                  int* __restrict__ cursor,
                                                  int* __restrict__ csr_src,
                                                  float* __restrict__ csr_ea) {
  int e = blockIdx.x * 256 + threadIdx.x;
  if (e >= NE) return;
  int s = ei[e];
  int d = ei[NE + e];
  int pos = atomicAdd(&cursor[d], 1);
  csr_src[pos] = s;
  csr_ea[pos] = ea[e];
}

// ============================ f32 GEMM ============================
// C[M,N] = A[M,K] @ B[K,N] (+ bias) (+= if ACC). M=16384, K%16==0, N%128==0.
// 128x128 tile, 256 threads, 8x8 per thread.

template<bool ACC>
__global__ __launch_bounds__(256) void gemm_f32(const float* __restrict__ A,
                                                const float* __restrict__ B,
                                                const float* __restrict__ bias,
                                                float* __restrict__ C,
                                                int K, int N) {
  __shared__ float As[16][132];
  __shared__ float Bs[16][132];
  int t = threadIdx.x;
  int bm = blockIdx.y * 128;
  int bn = blockIdx.x * 128;
  int ti = (t / 16) * 8;
  int tj = (t % 16) * 8;
  float acc[8][8] = {};

  int arow = t >> 2;          // 0..63
  int acol = (t & 3) * 4;     // 0,4,8,12
  int brow = t >> 5;          // 0..7
  int bcol = (t & 31) * 4;    // 0..124

  for (int k0 = 0; k0 < K; k0 += 16) {
    float4 a0 = *(const float4*)&A[(size_t)(bm + arow) * K + k0 + acol];
    float4 a1 = *(const float4*)&A[(size_t)(bm + arow + 64) * K + k0 + acol];
    float4 b0 = *(const float4*)&B[(size_t)(k0 + brow) * N + bn + bcol];
    float4 b1 = *(const float4*)&B[(size_t)(k0 + brow + 8) * N + bn + bcol];
    __syncthreads();
    As[acol + 0][arow] = a0.x; As[acol + 1][arow] = a0.y;
    As[acol + 2][arow] = a0.z; As[acol + 3][arow] = a0.w;
    As[acol + 0][arow + 64] = a1.x; As[acol + 1][arow + 64] = a1.y;
    As[acol + 2][arow + 64] = a1.z; As[acol + 3][arow + 64] = a1.w;
    *(float4*)&Bs[brow][bcol] = b0;
    *(float4*)&Bs[brow + 8][bcol] = b1;
    __syncthreads();
#pragma unroll
    for (int k = 0; k < 16; ++k) {
      float av[8], bv[8];
      *(float4*)&av[0] = *(const float4*)&As[k][ti];
      *(float4*)&av[4] = *(const float4*)&As[k][ti + 4];
      *(float4*)&bv[0] = *(const float4*)&Bs[k][tj];
      *(float4*)&bv[4] = *(const float4*)&Bs[k][tj + 4];
#pragma unroll
      for (int i = 0; i < 8; ++i)
#pragma unroll
        for (int j = 0; j < 8; ++j)
          acc[i][j] = fmaf(av[i], bv[j], acc[i][j]);
    }
  }

#pragma unroll
  for (int i = 0; i < 8; ++i) {
    float* crow = &C[(size_t)(bm + ti + i) * N + bn + tj];
#pragma unroll
    for (int j4 = 0; j4 < 2; ++j4) {
      float4 v;
      v.x = acc[i][j4 * 4 + 0]; v.y = acc[i][j4 * 4 + 1];
      v.z = acc[i][j4 * 4 + 2]; v.w = acc[i][j4 * 4 + 3];
      if (bias) {
        v.x += bias[bn + tj + j4 * 4 + 0]; v.y += bias[bn + tj + j4 * 4 + 1];
        v.z += bias[bn + tj + j4 * 4 + 2]; v.w += bias[bn + tj + j4 * 4 + 3];
      }
      if (ACC) {
        float4 old = *(float4*)&crow[j4 * 4];
        v.x += old.x; v.y += old.y; v.z += old.z; v.w += old.w;
      }
      *(float4*)&crow[j4 * 4] = v;
    }
  }
}

// ============================ GATv2 node aggregation ============================
// One wave per node; online softmax over {self-loop} ∪ incoming edges.

template<int H, int C>
__global__ __launch_bounds__(256) void gat_aggregate(
    const float* __restrict__ xl, const float* __restrict__ xr,
    const float* __restrict__ We, const float* __restrict__ att,
    const float* __restrict__ bo,
    const int* __restrict__ offs, const int* __restrict__ csr_src,
    const float* __restrict__ csr_ea, const float* __restrict__ loop_ea,
    float* __restrict__ out) {
  constexpr int D = H * C;
  constexpr int P = D / 64;
  constexpr int GROUP = C / P;   // lanes per head
  int n = (blockIdx.x * blockDim.x + threadIdx.x) >> 6;
  int lane = threadIdx.x & 63;
  if (n >= NN) return;
  int d0 = lane * P;

  float xrv[P], wev[P], attv[P];
  const float* xrrow = xr + (size_t)n * D;
  if constexpr (P == 4) {
    *(float4*)xrv = *(const float4*)&xrrow[d0];
    *(float4*)wev = *(const float4*)&We[d0];
    *(float4*)attv = *(const float4*)&att[d0];
  } else {
    *(float2*)xrv = *(const float2*)&xrrow[d0];
    *(float2*)wev = *(const float2*)&We[d0];
    *(float2*)attv = *(const float2*)&att[d0];
  }

  float m = -INFINITY, l = 0.f;
  float acc[P];
#pragma unroll
  for (int p = 0; p < P; ++p) acc[p] = 0.f;

  int beg = offs[n];
  int cnt = offs[n + 1] - beg;

  for (int e = -1; e < cnt; ++e) {
    int src; float eav;
    if (e < 0) { src = n; eav = loop_ea[n]; }
    else { src = csr_src[beg + e]; eav = csr_ea[beg + e]; }
    const float* xlrow = xl + (size_t)src * D;
    float xv[P];
    if constexpr (P == 4) *(float4*)xv = *(const float4*)&xlrow[d0];
    else                  *(float2*)xv = *(const float2*)&xlrow[d0];

    float partial = 0.f;
#pragma unroll
    for (int p = 0; p < P; ++p) {
      float s = xv[p] + xrv[p] + eav * wev[p];
      s = (s > 0.f) ? s : 0.2f * s;      // leaky_relu 0.2
      partial = fmaf(s, attv[p], partial);
    }
#pragma unroll
    for (int w = 1; w < GROUP; w <<= 1) partial += __shfl_xor(partial, w, 64);
    float alpha = partial;

    float nm = fmaxf(m, alpha);
    float sc = expf(m - nm);
    float pe = expf(alpha - nm);
    l = l * sc + pe;
#pragma unroll
    for (int p = 0; p < P; ++p) acc[p] = fmaf(acc[p], sc, pe * xv[p]);
    m = nm;
  }

  float inv = 1.f / l;
  float* orow = out + (size_t)n * D;
#pragma unroll
  for (int p = 0; p < P; ++p) orow[d0 + p] = fmaf(acc[p], inv, bo[d0 + p]);
}

// ============================ LayerNorm (+GELU) (+residual) ============================

template<int P, bool GELU, bool RES>
__global__ __launch_bounds__(256) void post_ln(const float* __restrict__ in,
                                               const float* __restrict__ g,
                                               const float* __restrict__ b,
                                               const float* __restrict__ res,
                                               float* __restrict__ out) {
  constexpr int D = P * 64;
  int n = (blockIdx.x * blockDim.x + threadIdx.x) >> 6;
  int lane = threadIdx.x & 63;
  if (n >= NN) return;
  int d0 = lane * P;
  const float* row = in + (size_t)n * D;
  float v[P];
  if constexpr (P == 4) *(float4*)v = *(const float4*)&row[d0];
  else                  *(float2*)v = *(const float2*)&row[d0];

  float s = 0.f, s2 = 0.f;
#pragma unroll
  for (int p = 0; p < P; ++p) { s += v[p]; s2 = fmaf(v[p], v[p], s2); }
#pragma unroll
  for (int w = 1; w < 64; w <<= 1) {
    s += __shfl_xor(s, w, 64);
    s2 += __shfl_xor(s2, w, 64);
  }
  float mu = s * (1.f / D);
  float var = s2 * (1.f / D) - mu * mu;
  float r = rsqrtf(var + 1e-5f);

  float o[P];
#pragma unroll
  for (int p = 0; p < P; ++p) {
    float y = (v[p] - mu) * r * g[d0 + p] + b[d0 + p];
    if (GELU) y = 0.5f * y * (1.f + erff(y * 0.70710678118654752f));
    if (RES) y += res[(size_t)n * D + d0 + p];
    o[p] = y;
  }
  float* orow = out + (size_t)n * D;
  if constexpr (P == 4) *(float4*)&orow[d0] = *(float4*)o;
  else                  *(float2*)&orow[d0] = *(float2*)o;
}

// ============================ pooling ============================

__device__ __forceinline__ int lower_bound_i(const int* arr, int n, int val) {
  int lo = 0, hi = n;
  while (lo < hi) {
    int mid = (lo + hi) >> 1;
    if (arr[mid] < val) lo = mid + 1; else hi = mid;
  }
  return lo;
}

__global__ __launch_bounds__(128) void k_pool(const float* __restrict__ h3,
                                              const int* __restrict__ batch,
                                              float* __restrict__ out) {
  int gidx = blockIdx.x;
  int d = threadIdx.x;
  int lo = lower_bound_i(batch, NN, gidx);
  int hi = lower_bound_i(batch, NN, gidx + 1);
  float s = 0.f;
  for (int n = lo; n < hi; ++n) s += h3[(size_t)n * DOUT3 + d];
  int cnt = hi - lo;
  out[gidx * DOUT3 + d] = s / fmaxf((float)cnt, 1.f);
}

// ============================ launch ============================

extern "C" void kernel_launch(void* const* d_in, const int* in_sizes, int n_in,
                              void* d_out, int out_size, void* d_ws, size_t ws_size,
                              hipStream_t stream) {
  const float* x   = (const float*)d_in[0];
  const int*   ei  = (const int*)d_in[1];
  const float* ea  = (const float*)d_in[2];
  const int*   bat = (const int*)d_in[3];
  // d_in[4] = num_graphs (256, hardcoded)
  const float* Wl1 = (const float*)d_in[5];  const float* bl1 = (const float*)d_in[6];
  const float* Wr1 = (const float*)d_in[7];  const float* br1 = (const float*)d_in[8];
  const float* We1 = (const float*)d_in[9];  const float* at1 = (const float*)d_in[10];
  const float* bo1 = (const float*)d_in[11];
  const float* Wl2 = (const float*)d_in[12]; const float* bl2 = (const float*)d_in[13];
  const float* Wr2 = (const float*)d_in[14]; const float* br2 = (const float*)d_in[15];
  const float* We2 = (const float*)d_in[16]; const float* at2 = (const float*)d_in[17];
  const float* bo2 = (const float*)d_in[18];
  const float* Wl3 = (const float*)d_in[19]; const float* bl3 = (const float*)d_in[20];
  const float* Wr3 = (const float*)d_in[21]; const float* br3 = (const float*)d_in[22];
  const float* We3 = (const float*)d_in[23]; const float* at3 = (const float*)d_in[24];
  const float* bo3 = (const float*)d_in[25];
  const float* g1 = (const float*)d_in[26]; const float* b1 = (const float*)d_in[27];
  const float* g2 = (const float*)d_in[28]; const float* b2 = (const float*)d_in[29];
  const float* g3 = (const float*)d_in[30]; const float* b3 = (const float*)d_in[31];
  const float* Wres = (const float*)d_in[32];
  float* out = (float*)d_out;

  char* ws = (char*)d_ws;
  size_t off = 0;
  float* xl  = (float*)(ws + off); off += (size_t)NN * DHID * 4;
  float* xr  = (float*)(ws + off); off += (size_t)NN * DHID * 4;
  float* gat = (float*)(ws + off); off += (size_t)NN * DHID * 4;
  float* hb  = (float*)(ws + off); off += (size_t)NN * DHID * 4;
  int*   deg    = (int*)(ws + off); off += NN * 4;
  int*   offs   = (int*)(ws + off); off += (NN + 1) * 4 + 60;  // keep 64B align
  int*   cursor = (int*)(ws + off); off += NN * 4;
  float* easum  = (float*)(ws + off); off += NN * 4;
  int*   csr_src = (int*)(ws + off); off += (size_t)NE * 4;
  float* csr_ea  = (float*)(ws + off); off += (size_t)NE * 4;

  // ---- CSR build ----
  hipMemsetAsync(deg, 0, NN * 4, stream);
  hipMemsetAsync(easum, 0, NN * 4, stream);
  k_edge_count<<<NE / 256, 256, 0, stream>>>(ei, ea, deg, easum);
  k_scan<<<1, 1024, 0, stream>>>(deg, easum, offs, cursor);
  k_fill_csr<<<NE / 256, 256, 0, stream>>>(ei, ea, cursor, csr_src, csr_ea);

  dim3 blk(256);
  dim3 grid_n256(DHID / 128, NN / 128);   // (2,128)
  dim3 grid_n128(DOUT3 / 128, NN / 128);  // (1,128)
  int nwave_blocks = NN / 4;              // 4 waves/block, 1 node/wave

  // ---- layer 1 ----
  gemm_f32<false><<<grid_n256, blk, 0, stream>>>(x, Wl1, bl1, xl, KDIM1, DHID);
  gemm_f32<false><<<grid_n256, blk, 0, stream>>>(x, Wr1, br1, xr, KDIM1, DHID);
  gat_aggregate<4, 64><<<nwave_blocks, blk, 0, stream>>>(xl, xr, We1, at1, bo1,
                                                         offs, csr_src, csr_ea, easum, gat);
  post_ln<4, true, false><<<nwave_blocks, blk, 0, stream>>>(gat, g1, b1, nullptr, hb);
  gemm_f32<true><<<grid_n256, blk, 0, stream>>>(x, Wres, nullptr, hb, KDIM1, DHID);

  // ---- layer 2 ----
  gemm_f32<false><<<grid_n256, blk, 0, stream>>>(hb, Wl2, bl2, xl, DHID, DHID);
  gemm_f32<false><<<grid_n256, blk, 0, stream>>>(hb, Wr2, br2, xr, DHID, DHID);
  gat_aggregate<4, 64><<<nwave_blocks, blk, 0, stream>>>(xl, xr, We2, at2, bo2,
                                                         offs, csr_src, csr_ea, easum, gat);
  post_ln<4, true, true><<<nwave_blocks, blk, 0, stream>>>(gat, g2, b2, hb, hb);

  // ---- layer 3 ----
  gemm_f32<false><<<grid_n128, blk, 0, stream>>>(hb, Wl3, bl3, xl, DHID, DOUT3);
  gemm_f32<false><<<grid_n128, blk, 0, stream>>>(hb, Wr3, br3, xr, DHID, DOUT3);
  gat_aggregate<1, 128><<<nwave_blocks, blk, 0, stream>>>(xl, xr, We3, at3, bo3,
                                                          offs, csr_src, csr_ea, easum, gat);
  post_ln<2, false, false><<<nwave_blocks, blk, 0, stream>>>(gat, g3, b3, nullptr, hb);

  // ---- pooling ----
  k_pool<<<NG, 128, 0, stream>>>(hb, bat, out);
}

// Round 7
// 381.709 us; speedup vs baseline: 1.6118x; 1.6118x over previous
//
#include <hip/hip_runtime.h>
#include <hip/hip_bf16.h>
#include <math.h>

#define NN 16384     // nodes
#define NE 262144    // edges
#define KDIM1 480
#define DHID 256
#define DOUT3 128
#define NG 256       // graphs

typedef short bf16x8 __attribute__((ext_vector_type(8)));
typedef float f32x4 __attribute__((ext_vector_type(4)));

__device__ __forceinline__ unsigned short f2bf(float f) {
  unsigned u = __float_as_uint(f);
  unsigned r = (u + 0x7fffu + ((u >> 16) & 1u)) >> 16;
  return (unsigned short)r;
}

__device__ __forceinline__ void gload_lds16(const void* g, void* l) {
  __builtin_amdgcn_global_load_lds((const __attribute__((address_space(1))) void*)g,
                                   (__attribute__((address_space(3))) void*)l,
                                   16, 0, 0);
}

// ============================ CSR build ============================

__global__ __launch_bounds__(256) void k_edge_count(const int* __restrict__ ei,
                                                    const float* __restrict__ ea,
                                                    int* __restrict__ deg,
                                                    float* __restrict__ easum) {
  int e = blockIdx.x * 256 + threadIdx.x;
  if (e >= NE) return;
  int d = ei[NE + e];
  atomicAdd(&deg[d], 1);
  atomicAdd(&easum[d], ea[e]);
}

__global__ __launch_bounds__(1024) void k_scan(const int* __restrict__ deg,
                                               float* __restrict__ easum,
                                               int* __restrict__ offs,
                                               int* __restrict__ cursor) {
  __shared__ int sums[1024];
  int t = threadIdx.x;
  int base = t * 16;
  int local[16];
  int s = 0;
#pragma unroll
  for (int i = 0; i < 16; ++i) { local[i] = deg[base + i]; s += local[i]; }
  sums[t] = s;
  __syncthreads();
  for (int d = 1; d < 1024; d <<= 1) {
    int v = (t >= d) ? sums[t - d] : 0;
    __syncthreads();
    sums[t] += v;
    __syncthreads();
  }
  int prefix = (t == 0) ? 0 : sums[t - 1];
#pragma unroll
  for (int i = 0; i < 16; ++i) {
    offs[base + i] = prefix;
    cursor[base + i] = prefix;
    prefix += local[i];
  }
  if (t == 1023) offs[NN] = prefix;
#pragma unroll
  for (int i = 0; i < 16; ++i) {
    easum[base + i] = easum[base + i] / fmaxf((float)local[i], 1.f);
  }
}

__global__ __launch_bounds__(256) void k_fill_csr(const int* __restrict__ ei,
                                                  const float* __restrict__ ea,
                                                  int* __restrict__ cursor,
                                                  int* __restrict__ csr_src,
                                                  float* __restrict__ csr_ea) {
  int e = blockIdx.x * 256 + threadIdx.x;
  if (e >= NE) return;
  int s = ei[e];
  int d = ei[NE + e];
  int pos = atomicAdd(&cursor[d], 1);
  csr_src[pos] = s;
  csr_ea[pos] = ea[e];
}

// ============================ conversions ============================

__global__ __launch_bounds__(256) void k_f32_to_bf16(const float* __restrict__ in,
                                                     unsigned short* __restrict__ out,
                                                     int n) {
  int i = (blockIdx.x * 256 + threadIdx.x) * 4;
  if (i >= n) return;
  float4 v = *(const float4*)&in[i];
  ushort4 o;
  o.x = f2bf(v.x); o.y = f2bf(v.y); o.z = f2bf(v.z); o.w = f2bf(v.w);
  *(ushort4*)&out[i] = o;
}

// Wt[n][k] = bf16(W[k][n]); writes coalesced along k.
__global__ __launch_bounds__(256) void k_transpose_bf16(const float* __restrict__ W,
                                                        unsigned short* __restrict__ Wt,
                                                        int K, int N) {
  int idx = blockIdx.x * 256 + threadIdx.x;
  if (idx >= K * N) return;
  int n = idx / K, k = idx % K;
  Wt[idx] = f2bf(W[(size_t)k * N + n]);
}

// ============================ bf16 MFMA GEMM ============================
// C[M,N] = A[M,K](bf16) @ Bt[N,K](bf16)^T (+bias) (+=C if ACC), f32 out.
// 64x64 tile, BK=32, 4 waves (2x2), wave tile 32x32 (2x2 16x16 frags).
// K % 32 == 0, N % 64 == 0, M % 64 == 0.

template<bool ACC>
__global__ __launch_bounds__(256) void gemm_bf16(const short* __restrict__ A,
                                                 const short* __restrict__ Bt,
                                                 const float* __restrict__ bias,
                                                 float* __restrict__ C,
                                                 int K, int N) {
  __shared__ short As[64 * 32];
  __shared__ short Bs[64 * 32];
  int t = threadIdx.x;
  int w = t >> 6;
  int lane = t & 63;
  int bm = blockIdx.y * 64;
  int bn = blockIdx.x * 64;
  int wr = w >> 1, wc = w & 1;

  // staging: wave w covers rows [16w,16w+16) of each tile; lane covers
  // row 16w + lane/4, 16-byte chunk lane%4. LDS linear [64][32] bf16 (64B rows):
  // LDS byte off = w*1024 + lane*16 == (16w + lane/4)*64 + (lane%4)*16.
  const short* Ag = A + (size_t)(bm + w * 16 + (lane >> 2)) * K + (lane & 3) * 8;
  const short* Bg = Bt + (size_t)(bn + w * 16 + (lane >> 2)) * K + (lane & 3) * 8;
  short* Al = &As[w * 16 * 32];
  short* Bl = &Bs[w * 16 * 32];

  f32x4 acc[2][2] = {};

  int ar0 = (wr * 32 + (lane & 15)) * 32 + (lane >> 4) * 8;
  int br0 = (wc * 32 + (lane & 15)) * 32 + (lane >> 4) * 8;

  for (int k0 = 0; k0 < K; k0 += 32) {
    gload_lds16(Ag, Al);
    gload_lds16(Bg, Bl);
    Ag += 32; Bg += 32;
    __syncthreads();   // drains vmcnt -> tiles visible
    bf16x8 a0 = *(const bf16x8*)&As[ar0];
    bf16x8 a1 = *(const bf16x8*)&As[ar0 + 16 * 32];
    bf16x8 b0 = *(const bf16x8*)&Bs[br0];
    bf16x8 b1 = *(const bf16x8*)&Bs[br0 + 16 * 32];
    acc[0][0] = __builtin_amdgcn_mfma_f32_16x16x32_bf16(a0, b0, acc[0][0], 0, 0, 0);
    acc[0][1] = __builtin_amdgcn_mfma_f32_16x16x32_bf16(a0, b1, acc[0][1], 0, 0, 0);
    acc[1][0] = __builtin_amdgcn_mfma_f32_16x16x32_bf16(a1, b0, acc[1][0], 0, 0, 0);
    acc[1][1] = __builtin_amdgcn_mfma_f32_16x16x32_bf16(a1, b1, acc[1][1], 0, 0, 0);
    __syncthreads();   // all reads done before next stage overwrites
  }

  // C/D layout: col = lane&15, row = (lane>>4)*4 + r   [m89-verified]
  int col = lane & 15;
  int row4 = (lane >> 4) * 4;
#pragma unroll
  for (int mi = 0; mi < 2; ++mi) {
#pragma unroll
    for (int ni = 0; ni < 2; ++ni) {
      f32x4 a = acc[mi][ni];
      int gc = bn + wc * 32 + ni * 16 + col;
      float bv = bias ? bias[gc] : 0.f;
#pragma unroll
      for (int r = 0; r < 4; ++r) {
        int gr = bm + wr * 32 + mi * 16 + row4 + r;
        size_t o = (size_t)gr * N + gc;
        float v = a[r] + bv;
        if (ACC) v += C[o];
        C[o] = v;
      }
    }
  }
}

// ============================ GATv2 node aggregation ============================

template<int H, int C>
__global__ __launch_bounds__(256) void gat_aggregate(
    const float* __restrict__ xl, const float* __restrict__ xr,
    const float* __restrict__ We, const float* __restrict__ att,
    const float* __restrict__ bo,
    const int* __restrict__ offs, const int* __restrict__ csr_src,
    const float* __restrict__ csr_ea, const float* __restrict__ loop_ea,
    float* __restrict__ out) {
  constexpr int D = H * C;
  constexpr int P = D / 64;
  constexpr int GROUP = C / P;   // lanes per head
  int n = (blockIdx.x * blockDim.x + threadIdx.x) >> 6;
  int lane = threadIdx.x & 63;
  if (n >= NN) return;
  int d0 = lane * P;

  float xrv[P], wev[P], attv[P];
  const float* xrrow = xr + (size_t)n * D;
  if constexpr (P == 4) {
    *(float4*)xrv = *(const float4*)&xrrow[d0];
    *(float4*)wev = *(const float4*)&We[d0];
    *(float4*)attv = *(const float4*)&att[d0];
  } else {
    *(float2*)xrv = *(const float2*)&xrrow[d0];
    *(float2*)wev = *(const float2*)&We[d0];
    *(float2*)attv = *(const float2*)&att[d0];
  }

  float m = -INFINITY, l = 0.f;
  float acc[P];
#pragma unroll
  for (int p = 0; p < P; ++p) acc[p] = 0.f;

  int beg = offs[n];
  int cnt = offs[n + 1] - beg;

  for (int e = -1; e < cnt; ++e) {
    int src; float eav;
    if (e < 0) { src = n; eav = loop_ea[n]; }
    else { src = csr_src[beg + e]; eav = csr_ea[beg + e]; }
    const float* xlrow = xl + (size_t)src * D;
    float xv[P];
    if constexpr (P == 4) *(float4*)xv = *(const float4*)&xlrow[d0];
    else                  *(float2*)xv = *(const float2*)&xlrow[d0];

    float partial = 0.f;
#pragma unroll
    for (int p = 0; p < P; ++p) {
      float s = xv[p] + xrv[p] + eav * wev[p];
      s = (s > 0.f) ? s : 0.2f * s;      // leaky_relu 0.2
      partial = fmaf(s, attv[p], partial);
    }
#pragma unroll
    for (int w = 1; w < GROUP; w <<= 1) partial += __shfl_xor(partial, w, 64);
    float alpha = partial;

    float nm = fmaxf(m, alpha);
    float sc = expf(m - nm);
    float pe = expf(alpha - nm);
    l = l * sc + pe;
#pragma unroll
    for (int p = 0; p < P; ++p) acc[p] = fmaf(acc[p], sc, pe * xv[p]);
    m = nm;
  }

  float inv = 1.f / l;
  float* orow = out + (size_t)n * D;
#pragma unroll
  for (int p = 0; p < P; ++p) orow[d0 + p] = fmaf(acc[p], inv, bo[d0 + p]);
}

// ============================ LayerNorm (+GELU) (+residual) ============================

template<int P, bool GELU, bool RES>
__global__ __launch_bounds__(256) void post_ln(const float* __restrict__ in,
                                               const float* __restrict__ g,
                                               const float* __restrict__ b,
                                               const float* __restrict__ res,
                                               float* __restrict__ out) {
  constexpr int D = P * 64;
  int n = (blockIdx.x * blockDim.x + threadIdx.x) >> 6;
  int lane = threadIdx.x & 63;
  if (n >= NN) return;
  int d0 = lane * P;
  const float* row = in + (size_t)n * D;
  float v[P];
  if constexpr (P == 4) *(float4*)v = *(const float4*)&row[d0];
  else                  *(float2*)v = *(const float2*)&row[d0];

  float s = 0.f, s2 = 0.f;
#pragma unroll
  for (int p = 0; p < P; ++p) { s += v[p]; s2 = fmaf(v[p], v[p], s2); }
#pragma unroll
  for (int w = 1; w < 64; w <<= 1) {
    s += __shfl_xor(s, w, 64);
    s2 += __shfl_xor(s2, w, 64);
  }
  float mu = s * (1.f / D);
  float var = s2 * (1.f / D) - mu * mu;
  float r = rsqrtf(var + 1e-5f);

  float o[P];
#pragma unroll
  for (int p = 0; p < P; ++p) {
    float y = (v[p] - mu) * r * g[d0 + p] + b[d0 + p];
    if (GELU) y = 0.5f * y * (1.f + erff(y * 0.70710678118654752f));
    if (RES) y += res[(size_t)n * D + d0 + p];
    o[p] = y;
  }
  float* orow = out + (size_t)n * D;
  if constexpr (P == 4) *(float4*)&orow[d0] = *(float4*)o;
  else                  *(float2*)&orow[d0] = *(float2*)o;
}

// ============================ pooling ============================

__device__ __forceinline__ int lower_bound_i(const int* arr, int n, int val) {
  int lo = 0, hi = n;
  while (lo < hi) {
    int mid = (lo + hi) >> 1;
    if (arr[mid] < val) lo = mid + 1; else hi = mid;
  }
  return lo;
}

__global__ __launch_bounds__(128) void k_pool(const float* __restrict__ h3,
                                              const int* __restrict__ batch,
                                              float* __restrict__ out) {
  int gidx = blockIdx.x;
  int d = threadIdx.x;
  int lo = lower_bound_i(batch, NN, gidx);
  int hi = lower_bound_i(batch, NN, gidx + 1);
  float s = 0.f;
  for (int n = lo; n < hi; ++n) s += h3[(size_t)n * DOUT3 + d];
  int cnt = hi - lo;
  out[gidx * DOUT3 + d] = s / fmaxf((float)cnt, 1.f);
}

// ============================ launch ============================

extern "C" void kernel_launch(void* const* d_in, const int* in_sizes, int n_in,
                              void* d_out, int out_size, void* d_ws, size_t ws_size,
                              hipStream_t stream) {
  const float* x   = (const float*)d_in[0];
  const int*   ei  = (const int*)d_in[1];
  const float* ea  = (const float*)d_in[2];
  const int*   bat = (const int*)d_in[3];
  // d_in[4] = num_graphs (256, hardcoded)
  const float* Wl1 = (const float*)d_in[5];  const float* bl1 = (const float*)d_in[6];
  const float* Wr1 = (const float*)d_in[7];  const float* br1 = (const float*)d_in[8];
  const float* We1 = (const float*)d_in[9];  const float* at1 = (const float*)d_in[10];
  const float* bo1 = (const float*)d_in[11];
  const float* Wl2 = (const float*)d_in[12]; const float* bl2 = (const float*)d_in[13];
  const float* Wr2 = (const float*)d_in[14]; const float* br2 = (const float*)d_in[15];
  const float* We2 = (const float*)d_in[16]; const float* at2 = (const float*)d_in[17];
  const float* bo2 = (const float*)d_in[18];
  const float* Wl3 = (const float*)d_in[19]; const float* bl3 = (const float*)d_in[20];
  const float* Wr3 = (const float*)d_in[21]; const float* br3 = (const float*)d_in[22];
  const float* We3 = (const float*)d_in[23]; const float* at3 = (const float*)d_in[24];
  const float* bo3 = (const float*)d_in[25];
  const float* g1 = (const float*)d_in[26]; const float* b1 = (const float*)d_in[27];
  const float* g2 = (const float*)d_in[28]; const float* b2 = (const float*)d_in[29];
  const float* g3 = (const float*)d_in[30]; const float* b3 = (const float*)d_in[31];
  const float* Wres = (const float*)d_in[32];
  float* out = (float*)d_out;

  char* ws = (char*)d_ws;
  size_t off = 0;
  float* xl  = (float*)(ws + off); off += (size_t)NN * DHID * 4;
  float* xr  = (float*)(ws + off); off += (size_t)NN * DHID * 4;
  float* gat = (float*)(ws + off); off += (size_t)NN * DHID * 4;
  float* hb  = (float*)(ws + off); off += (size_t)NN * DHID * 4;
  int*   deg    = (int*)(ws + off); off += NN * 4;
  int*   offs   = (int*)(ws + off); off += (NN + 1) * 4 + 60;  // keep 64B align
  int*   cursor = (int*)(ws + off); off += NN * 4;
  float* easum  = (float*)(ws + off); off += NN * 4;
  int*   csr_src = (int*)(ws + off); off += (size_t)NE * 4;
  float* csr_ea  = (float*)(ws + off); off += (size_t)NE * 4;
  // bf16 buffers
  unsigned short* actb = (unsigned short*)(ws + off); off += (size_t)NN * KDIM1 * 2;  // x (then hb) in bf16
  unsigned short* WtL1 = (unsigned short*)(ws + off); off += (size_t)DHID * KDIM1 * 2;
  unsigned short* WtR1 = (unsigned short*)(ws + off); off += (size_t)DHID * KDIM1 * 2;
  unsigned short* WtRs = (unsigned short*)(ws + off); off += (size_t)DHID * KDIM1 * 2;
  unsigned short* WtL2 = (unsigned short*)(ws + off); off += (size_t)DHID * DHID * 2;
  unsigned short* WtR2 = (unsigned short*)(ws + off); off += (size_t)DHID * DHID * 2;
  unsigned short* WtL3 = (unsigned short*)(ws + off); off += (size_t)DOUT3 * DHID * 2;
  unsigned short* WtR3 = (unsigned short*)(ws + off); off += (size_t)DOUT3 * DHID * 2;

  // ---- CSR build + conversions ----
  hipMemsetAsync(deg, 0, NN * 4, stream);
  hipMemsetAsync(easum, 0, NN * 4, stream);
  k_edge_count<<<NE / 256, 256, 0, stream>>>(ei, ea, deg, easum);
  k_scan<<<1, 1024, 0, stream>>>(deg, easum, offs, cursor);
  k_fill_csr<<<NE / 256, 256, 0, stream>>>(ei, ea, cursor, csr_src, csr_ea);

  k_f32_to_bf16<<<(NN * KDIM1 / 4 + 255) / 256, 256, 0, stream>>>(x, actb, NN * KDIM1);
  k_transpose_bf16<<<(DHID * KDIM1 + 255) / 256, 256, 0, stream>>>(Wl1, WtL1, KDIM1, DHID);
  k_transpose_bf16<<<(DHID * KDIM1 + 255) / 256, 256, 0, stream>>>(Wr1, WtR1, KDIM1, DHID);
  k_transpose_bf16<<<(DHID * KDIM1 + 255) / 256, 256, 0, stream>>>(Wres, WtRs, KDIM1, DHID);
  k_transpose_bf16<<<(DHID * DHID + 255) / 256, 256, 0, stream>>>(Wl2, WtL2, DHID, DHID);
  k_transpose_bf16<<<(DHID * DHID + 255) / 256, 256, 0, stream>>>(Wr2, WtR2, DHID, DHID);
  k_transpose_bf16<<<(DOUT3 * DHID + 255) / 256, 256, 0, stream>>>(Wl3, WtL3, DHID, DOUT3);
  k_transpose_bf16<<<(DOUT3 * DHID + 255) / 256, 256, 0, stream>>>(Wr3, WtR3, DHID, DOUT3);

  dim3 blk(256);
  dim3 g256(DHID / 64, NN / 64);    // (4, 256)
  dim3 g128(DOUT3 / 64, NN / 64);   // (2, 256)
  int nwave_blocks = NN / 4;

  // ---- layer 1 ----
  gemm_bf16<false><<<g256, blk, 0, stream>>>((const short*)actb, (const short*)WtL1, bl1, xl, KDIM1, DHID);
  gemm_bf16<false><<<g256, blk, 0, stream>>>((const short*)actb, (const short*)WtR1, br1, xr, KDIM1, DHID);
  gat_aggregate<4, 64><<<nwave_blocks, blk, 0, stream>>>(xl, xr, We1, at1, bo1,
                                                         offs, csr_src, csr_ea, easum, gat);
  post_ln<4, true, false><<<nwave_blocks, blk, 0, stream>>>(gat, g1, b1, nullptr, hb);
  gemm_bf16<true><<<g256, blk, 0, stream>>>((const short*)actb, (const short*)WtRs, nullptr, hb, KDIM1, DHID);
  k_f32_to_bf16<<<(NN * DHID / 4 + 255) / 256, 256, 0, stream>>>(hb, actb, NN * DHID);

  // ---- layer 2 ----
  gemm_bf16<false><<<g256, blk, 0, stream>>>((const short*)actb, (const short*)WtL2, bl2, xl, DHID, DHID);
  gemm_bf16<false><<<g256, blk, 0, stream>>>((const short*)actb, (const short*)WtR2, br2, xr, DHID, DHID);
  gat_aggregate<4, 64><<<nwave_blocks, blk, 0, stream>>>(xl, xr, We2, at2, bo2,
                                                         offs, csr_src, csr_ea, easum, gat);
  post_ln<4, true, true><<<nwave_blocks, blk, 0, stream>>>(gat, g2, b2, hb, hb);
  k_f32_to_bf16<<<(NN * DHID / 4 + 255) / 256, 256, 0, stream>>>(hb, actb, NN * DHID);

  // ---- layer 3 ----
  gemm_bf16<false><<<g128, blk, 0, stream>>>((const short*)actb, (const short*)WtL3, bl3, xl, DHID, DOUT3);
  gemm_bf16<false><<<g128, blk, 0, stream>>>((const short*)actb, (const short*)WtR3, br3, xr, DHID, DOUT3);
  gat_aggregate<1, 128><<<nwave_blocks, blk, 0, stream>>>(xl, xr, We3, at3, bo3,
                                                          offs, csr_src, csr_ea, easum, gat);
  post_ln<2, false, false><<<nwave_blocks, blk, 0, stream>>>(gat, g3, b3, nullptr, hb);

  // ---- pooling ----
  k_pool<<<NG, 128, 0, stream>>>(hb, bat, out);
}

// Round 8
// 331.748 us; speedup vs baseline: 1.8545x; 1.1506x over previous
//
#include <hip/hip_runtime.h>
#include <hip/hip_bf16.h>
#include <math.h>

#define NN 16384     // nodes
#define NE 262144    // edges
#define KDIM1 480
#define DHID 256
#define DOUT3 128
#define NG 256       // graphs

typedef short bf16x8 __attribute__((ext_vector_type(8)));
typedef float f32x4 __attribute__((ext_vector_type(4)));

__device__ __forceinline__ unsigned short f2bf(float f) {
  unsigned u = __float_as_uint(f);
  unsigned r = (u + 0x7fffu + ((u >> 16) & 1u)) >> 16;
  return (unsigned short)r;
}
__device__ __forceinline__ float bf2f(unsigned short u) {
  return __uint_as_float((unsigned)u << 16);
}

__device__ __forceinline__ void gload_lds16(const void* g, void* l) {
  __builtin_amdgcn_global_load_lds((const __attribute__((address_space(1))) void*)g,
                                   (__attribute__((address_space(3))) void*)l,
                                   16, 0, 0);
}

// ============================ CSR build ============================

__global__ __launch_bounds__(256) void k_edge_count(const int* __restrict__ ei,
                                                    const float* __restrict__ ea,
                                                    int* __restrict__ deg,
                                                    float* __restrict__ easum) {
  int e = blockIdx.x * 256 + threadIdx.x;
  if (e >= NE) return;
  int d = ei[NE + e];
  atomicAdd(&deg[d], 1);
  atomicAdd(&easum[d], ea[e]);
}

__global__ __launch_bounds__(1024) void k_scan(const int* __restrict__ deg,
                                               float* __restrict__ easum,
                                               int* __restrict__ offs,
                                               int* __restrict__ cursor) {
  __shared__ int sums[1024];
  int t = threadIdx.x;
  int base = t * 16;
  int local[16];
  int s = 0;
#pragma unroll
  for (int i = 0; i < 16; ++i) { local[i] = deg[base + i]; s += local[i]; }
  sums[t] = s;
  __syncthreads();
  for (int d = 1; d < 1024; d <<= 1) {
    int v = (t >= d) ? sums[t - d] : 0;
    __syncthreads();
    sums[t] += v;
    __syncthreads();
  }
  int prefix = (t == 0) ? 0 : sums[t - 1];
#pragma unroll
  for (int i = 0; i < 16; ++i) {
    offs[base + i] = prefix;
    cursor[base + i] = prefix;
    prefix += local[i];
  }
  if (t == 1023) offs[NN] = prefix;
#pragma unroll
  for (int i = 0; i < 16; ++i) {
    easum[base + i] = easum[base + i] / fmaxf((float)local[i], 1.f);
  }
}

__global__ __launch_bounds__(256) void k_fill_csr(const int* __restrict__ ei,
                                                  const float* __restrict__ ea,
                                                  int* __restrict__ cursor,
                                                  int* __restrict__ csr_src,
                                                  float* __restrict__ csr_ea) {
  int e = blockIdx.x * 256 + threadIdx.x;
  if (e >= NE) return;
  int s = ei[e];
  int d = ei[NE + e];
  int pos = atomicAdd(&cursor[d], 1);
  csr_src[pos] = s;
  csr_ea[pos] = ea[e];
}

// ============================ conversions ============================

__global__ __launch_bounds__(256) void k_f32_to_bf16(const float* __restrict__ in,
                                                     unsigned short* __restrict__ out,
                                                     int n) {
  int i = (blockIdx.x * 256 + threadIdx.x) * 4;
  if (i >= n) return;
  float4 v = *(const float4*)&in[i];
  ushort4 o;
  o.x = f2bf(v.x); o.y = f2bf(v.y); o.z = f2bf(v.z); o.w = f2bf(v.w);
  *(ushort4*)&out[i] = o;
}

// Wt[n][k] = bf16(W[k][n])
__global__ __launch_bounds__(256) void k_transpose_bf16(const float* __restrict__ W,
                                                        unsigned short* __restrict__ Wt,
                                                        int K, int N) {
  int idx = blockIdx.x * 256 + threadIdx.x;
  if (idx >= K * N) return;
  int n = idx / K, k = idx % K;
  Wt[idx] = f2bf(W[(size_t)k * N + n]);
}

// Wt[n][k], n in [0,2*NH): n<NH -> Wl[k][n], else Wr[k][n-NH]
__global__ __launch_bounds__(256) void k_transpose_lr(const float* __restrict__ Wl,
                                                      const float* __restrict__ Wr,
                                                      unsigned short* __restrict__ Wt,
                                                      int K, int NH) {
  int idx = blockIdx.x * 256 + threadIdx.x;
  if (idx >= 2 * NH * K) return;
  int n = idx / K, k = idx % K;
  float v = (n < NH) ? Wl[(size_t)k * NH + n] : Wr[(size_t)k * NH + (n - NH)];
  Wt[idx] = f2bf(v);
}

// ============================ bf16 MFMA GEMM cores ============================
// Shared main loop: 64x64 tile, BK=32, 4 waves (2x2), wave tile 32x32.

#define GEMM_CORE(A_, Bt_, K_)                                                   \
  __shared__ short As[64 * 32];                                                  \
  __shared__ short Bs[64 * 32];                                                  \
  int t = threadIdx.x;                                                           \
  int w = t >> 6;                                                                \
  int lane = t & 63;                                                             \
  int bm = blockIdx.y * 64;                                                      \
  int bn = blockIdx.x * 64;                                                      \
  int wr = w >> 1, wc = w & 1;                                                   \
  const short* Ag = A_ + (size_t)(bm + w * 16 + (lane >> 2)) * K_ + (lane & 3) * 8; \
  const short* Bg = Bt_ + (size_t)(bn + w * 16 + (lane >> 2)) * K_ + (lane & 3) * 8; \
  short* Al = &As[w * 16 * 32];                                                  \
  short* Bl = &Bs[w * 16 * 32];                                                  \
  f32x4 acc[2][2] = {};                                                          \
  int ar0 = (wr * 32 + (lane & 15)) * 32 + (lane >> 4) * 8;                      \
  int br0 = (wc * 32 + (lane & 15)) * 32 + (lane >> 4) * 8;                      \
  for (int k0 = 0; k0 < K_; k0 += 32) {                                          \
    gload_lds16(Ag, Al);                                                         \
    gload_lds16(Bg, Bl);                                                         \
    Ag += 32; Bg += 32;                                                          \
    __syncthreads();                                                             \
    bf16x8 a0 = *(const bf16x8*)&As[ar0];                                        \
    bf16x8 a1 = *(const bf16x8*)&As[ar0 + 16 * 32];                              \
    bf16x8 b0 = *(const bf16x8*)&Bs[br0];                                        \
    bf16x8 b1 = *(const bf16x8*)&Bs[br0 + 16 * 32];                              \
    acc[0][0] = __builtin_amdgcn_mfma_f32_16x16x32_bf16(a0, b0, acc[0][0], 0, 0, 0); \
    acc[0][1] = __builtin_amdgcn_mfma_f32_16x16x32_bf16(a0, b1, acc[0][1], 0, 0, 0); \
    acc[1][0] = __builtin_amdgcn_mfma_f32_16x16x32_bf16(a1, b0, acc[1][0], 0, 0, 0); \
    acc[1][1] = __builtin_amdgcn_mfma_f32_16x16x32_bf16(a1, b1, acc[1][1], 0, 0, 0); \
    __syncthreads();                                                             \
  }                                                                              \
  int col = lane & 15;                                                           \
  int row4 = (lane >> 4) * 4;

// C left/right split, bf16 outputs. grid.x = 2*NH/64.
__global__ __launch_bounds__(256) void gemm_lr(const short* __restrict__ A,
                                               const short* __restrict__ Wt,
                                               const float* __restrict__ bl,
                                               const float* __restrict__ br,
                                               unsigned short* __restrict__ xlb,
                                               unsigned short* __restrict__ xrb,
                                               int K, int NH) {
  GEMM_CORE(A, Wt, K)
  bool right = (bn >= NH);
  unsigned short* outp = right ? xrb : xlb;
  const float* bias = right ? br : bl;
  int cbase = right ? bn - NH : bn;
#pragma unroll
  for (int mi = 0; mi < 2; ++mi) {
#pragma unroll
    for (int ni = 0; ni < 2; ++ni) {
      f32x4 a = acc[mi][ni];
      int gc = cbase + wc * 32 + ni * 16 + col;
      float bv = bias[gc];
#pragma unroll
      for (int r = 0; r < 4; ++r) {
        int gr = bm + wr * 32 + mi * 16 + row4 + r;
        outp[(size_t)gr * NH + gc] = f2bf(a[r] + bv);
      }
    }
  }
}

// Cf += A@Wt (f32); outb = bf16(result). For the Wres residual GEMM.
__global__ __launch_bounds__(256) void gemm_res(const short* __restrict__ A,
                                                const short* __restrict__ Wt,
                                                float* __restrict__ Cf,
                                                unsigned short* __restrict__ outb,
                                                int K, int N) {
  GEMM_CORE(A, Wt, K)
#pragma unroll
  for (int mi = 0; mi < 2; ++mi) {
#pragma unroll
    for (int ni = 0; ni < 2; ++ni) {
      f32x4 a = acc[mi][ni];
      int gc = bn + wc * 32 + ni * 16 + col;
#pragma unroll
      for (int r = 0; r < 4; ++r) {
        int gr = bm + wr * 32 + mi * 16 + row4 + r;
        size_t o = (size_t)gr * N + gc;
        float v = a[r] + Cf[o];
        Cf[o] = v;
        outb[o] = f2bf(v);
      }
    }
  }
}

// ============================ fused GATv2 + LN (+GELU) (+RES) ============================
// One wave per node; bf16 gather; online softmax; LN fused in-register.

template<int D, int H, bool GELU_, bool RES_, bool WF32, bool WBF16>
__global__ __launch_bounds__(256) void gat_fused(
    const unsigned short* __restrict__ xlb, const unsigned short* __restrict__ xrb,
    const float* __restrict__ We, const float* __restrict__ att,
    const float* __restrict__ bo,
    const int* __restrict__ offs, const int* __restrict__ csr_src,
    const float* __restrict__ csr_ea, const float* __restrict__ loop_ea,
    const float* __restrict__ g, const float* __restrict__ bln,
    const float* __restrict__ res,
    float* __restrict__ outf, unsigned short* __restrict__ outb) {
  constexpr int P = D / 64;
  constexpr int C = D / H;
  constexpr int GROUP = C / P;   // lanes per head
  int n = (blockIdx.x * blockDim.x + threadIdx.x) >> 6;
  int lane = threadIdx.x & 63;
  if (n >= NN) return;
  int d0 = lane * P;

  float xrv[P], wev[P], attv[P];
  if constexpr (P == 4) {
    ushort4 u = *(const ushort4*)&xrb[(size_t)n * D + d0];
    xrv[0] = bf2f(u.x); xrv[1] = bf2f(u.y); xrv[2] = bf2f(u.z); xrv[3] = bf2f(u.w);
    *(float4*)wev = *(const float4*)&We[d0];
    *(float4*)attv = *(const float4*)&att[d0];
  } else {
    ushort2 u = *(const ushort2*)&xrb[(size_t)n * D + d0];
    xrv[0] = bf2f(u.x); xrv[1] = bf2f(u.y);
    *(float2*)wev = *(const float2*)&We[d0];
    *(float2*)attv = *(const float2*)&att[d0];
  }

  float m = -INFINITY, l = 0.f;
  float acc[P];
#pragma unroll
  for (int p = 0; p < P; ++p) acc[p] = 0.f;

  int beg = offs[n];
  int cnt = offs[n + 1] - beg;

  for (int e = -1; e < cnt; ++e) {
    int src; float eav;
    if (e < 0) { src = n; eav = loop_ea[n]; }
    else { src = csr_src[beg + e]; eav = csr_ea[beg + e]; }
    float xv[P];
    if constexpr (P == 4) {
      ushort4 u = *(const ushort4*)&xlb[(size_t)src * D + d0];
      xv[0] = bf2f(u.x); xv[1] = bf2f(u.y); xv[2] = bf2f(u.z); xv[3] = bf2f(u.w);
    } else {
      ushort2 u = *(const ushort2*)&xlb[(size_t)src * D + d0];
      xv[0] = bf2f(u.x); xv[1] = bf2f(u.y);
    }

    float partial = 0.f;
#pragma unroll
    for (int p = 0; p < P; ++p) {
      float s = xv[p] + xrv[p] + eav * wev[p];
      s = (s > 0.f) ? s : 0.2f * s;      // leaky_relu 0.2
      partial = fmaf(s, attv[p], partial);
    }
#pragma unroll
    for (int w = 1; w < GROUP; w <<= 1) partial += __shfl_xor(partial, w, 64);
    float alpha = partial;

    float nm = fmaxf(m, alpha);
    float sc = expf(m - nm);
    float pe = expf(alpha - nm);
    l = l * sc + pe;
#pragma unroll
    for (int p = 0; p < P; ++p) acc[p] = fmaf(acc[p], sc, pe * xv[p]);
    m = nm;
  }

  float inv = 1.f / l;
  float y[P];
#pragma unroll
  for (int p = 0; p < P; ++p) y[p] = fmaf(acc[p], inv, bo[d0 + p]);

  // fused LayerNorm over the wave-held row
  float s = 0.f, s2 = 0.f;
#pragma unroll
  for (int p = 0; p < P; ++p) { s += y[p]; s2 = fmaf(y[p], y[p], s2); }
#pragma unroll
  for (int w = 1; w < 64; w <<= 1) {
    s += __shfl_xor(s, w, 64);
    s2 += __shfl_xor(s2, w, 64);
  }
  float mu = s * (1.f / D);
  float var = s2 * (1.f / D) - mu * mu;
  float rr = rsqrtf(var + 1e-5f);

  float z[P];
#pragma unroll
  for (int p = 0; p < P; ++p) {
    float v = (y[p] - mu) * rr * g[d0 + p] + bln[d0 + p];
    if (GELU_) v = 0.5f * v * (1.f + erff(v * 0.70710678118654752f));
    if (RES_) v += res[(size_t)n * D + d0 + p];
    z[p] = v;
  }
  if (WF32) {
    float* orow = outf + (size_t)n * D;
    if constexpr (P == 4) *(float4*)&orow[d0] = *(float4*)z;
    else                  *(float2*)&orow[d0] = *(float2*)z;
  }
  if (WBF16) {
    unsigned short* orow = outb + (size_t)n * D;
    if constexpr (P == 4) {
      ushort4 o; o.x = f2bf(z[0]); o.y = f2bf(z[1]); o.z = f2bf(z[2]); o.w = f2bf(z[3]);
      *(ushort4*)&orow[d0] = o;
    } else {
      ushort2 o; o.x = f2bf(z[0]); o.y = f2bf(z[1]);
      *(ushort2*)&orow[d0] = o;
    }
  }
}

// ============================ pooling ============================

__device__ __forceinline__ int lower_bound_i(const int* arr, int n, int val) {
  int lo = 0, hi = n;
  while (lo < hi) {
    int mid = (lo + hi) >> 1;
    if (arr[mid] < val) lo = mid + 1; else hi = mid;
  }
  return lo;
}

__global__ __launch_bounds__(128) void k_pool(const float* __restrict__ h3,
                                              const int* __restrict__ batch,
                                              float* __restrict__ out) {
  int gidx = blockIdx.x;
  int d = threadIdx.x;
  int lo = lower_bound_i(batch, NN, gidx);
  int hi = lower_bound_i(batch, NN, gidx + 1);
  float s = 0.f;
  for (int n = lo; n < hi; ++n) s += h3[(size_t)n * DOUT3 + d];
  int cnt = hi - lo;
  out[gidx * DOUT3 + d] = s / fmaxf((float)cnt, 1.f);
}

// ============================ launch ============================

extern "C" void kernel_launch(void* const* d_in, const int* in_sizes, int n_in,
                              void* d_out, int out_size, void* d_ws, size_t ws_size,
                              hipStream_t stream) {
  const float* x   = (const float*)d_in[0];
  const int*   ei  = (const int*)d_in[1];
  const float* ea  = (const float*)d_in[2];
  const int*   bat = (const int*)d_in[3];
  // d_in[4] = num_graphs (256, hardcoded)
  const float* Wl1 = (const float*)d_in[5];  const float* bl1 = (const float*)d_in[6];
  const float* Wr1 = (const float*)d_in[7];  const float* br1 = (const float*)d_in[8];
  const float* We1 = (const float*)d_in[9];  const float* at1 = (const float*)d_in[10];
  const float* bo1 = (const float*)d_in[11];
  const float* Wl2 = (const float*)d_in[12]; const float* bl2 = (const float*)d_in[13];
  const float* Wr2 = (const float*)d_in[14]; const float* br2 = (const float*)d_in[15];
  const float* We2 = (const float*)d_in[16]; const float* at2 = (const float*)d_in[17];
  const float* bo2 = (const float*)d_in[18];
  const float* Wl3 = (const float*)d_in[19]; const float* bl3 = (const float*)d_in[20];
  const float* Wr3 = (const float*)d_in[21]; const float* br3 = (const float*)d_in[22];
  const float* We3 = (const float*)d_in[23]; const float* at3 = (const float*)d_in[24];
  const float* bo3 = (const float*)d_in[25];
  const float* g1 = (const float*)d_in[26]; const float* b1 = (const float*)d_in[27];
  const float* g2 = (const float*)d_in[28]; const float* b2 = (const float*)d_in[29];
  const float* g3 = (const float*)d_in[30]; const float* b3 = (const float*)d_in[31];
  const float* Wres = (const float*)d_in[32];
  float* out = (float*)d_out;

  char* ws = (char*)d_ws;
  size_t off = 0;
  unsigned short* xlb = (unsigned short*)(ws + off); off += (size_t)NN * DHID * 2;
  unsigned short* xrb = (unsigned short*)(ws + off); off += (size_t)NN * DHID * 2;
  float* hb = (float*)(ws + off); off += (size_t)NN * DHID * 4;
  float* h3 = (float*)(ws + off); off += (size_t)NN * DOUT3 * 4;
  unsigned short* actb0 = (unsigned short*)(ws + off); off += (size_t)NN * KDIM1 * 2;
  unsigned short* actb1 = (unsigned short*)(ws + off); off += (size_t)NN * DHID * 2;
  int*   deg    = (int*)(ws + off); off += NN * 4;
  int*   offs   = (int*)(ws + off); off += (NN + 1) * 4 + 60;
  int*   cursor = (int*)(ws + off); off += NN * 4;
  float* easum  = (float*)(ws + off); off += NN * 4;
  int*   csr_src = (int*)(ws + off); off += (size_t)NE * 4;
  float* csr_ea  = (float*)(ws + off); off += (size_t)NE * 4;
  unsigned short* Wc1 = (unsigned short*)(ws + off); off += (size_t)2 * DHID * KDIM1 * 2;
  unsigned short* Wrs = (unsigned short*)(ws + off); off += (size_t)DHID * KDIM1 * 2;
  unsigned short* Wc2 = (unsigned short*)(ws + off); off += (size_t)2 * DHID * DHID * 2;
  unsigned short* Wc3 = (unsigned short*)(ws + off); off += (size_t)2 * DOUT3 * DHID * 2;

  // ---- CSR build + conversions ----
  hipMemsetAsync(deg, 0, NN * 4, stream);
  hipMemsetAsync(easum, 0, NN * 4, stream);
  k_edge_count<<<NE / 256, 256, 0, stream>>>(ei, ea, deg, easum);
  k_scan<<<1, 1024, 0, stream>>>(deg, easum, offs, cursor);
  k_fill_csr<<<NE / 256, 256, 0, stream>>>(ei, ea, cursor, csr_src, csr_ea);

  k_f32_to_bf16<<<(NN * KDIM1 / 4 + 255) / 256, 256, 0, stream>>>(x, actb0, NN * KDIM1);
  k_transpose_lr<<<(2 * DHID * KDIM1 + 255) / 256, 256, 0, stream>>>(Wl1, Wr1, Wc1, KDIM1, DHID);
  k_transpose_bf16<<<(DHID * KDIM1 + 255) / 256, 256, 0, stream>>>(Wres, Wrs, KDIM1, DHID);
  k_transpose_lr<<<(2 * DHID * DHID + 255) / 256, 256, 0, stream>>>(Wl2, Wr2, Wc2, DHID, DHID);
  k_transpose_lr<<<(2 * DOUT3 * DHID + 255) / 256, 256, 0, stream>>>(Wl3, Wr3, Wc3, DHID, DOUT3);

  dim3 blk(256);
  int nwave_blocks = NN / 4;

  // ---- layer 1 ----
  gemm_lr<<<dim3(2 * DHID / 64, NN / 64), blk, 0, stream>>>(
      (const short*)actb0, (const short*)Wc1, bl1, br1, xlb, xrb, KDIM1, DHID);
  gat_fused<DHID, 4, true, false, true, false><<<nwave_blocks, blk, 0, stream>>>(
      xlb, xrb, We1, at1, bo1, offs, csr_src, csr_ea, easum, g1, b1, nullptr, hb, nullptr);
  gemm_res<<<dim3(DHID / 64, NN / 64), blk, 0, stream>>>(
      (const short*)actb0, (const short*)Wrs, hb, actb1, KDIM1, DHID);

  // ---- layer 2 ----
  gemm_lr<<<dim3(2 * DHID / 64, NN / 64), blk, 0, stream>>>(
      (const short*)actb1, (const short*)Wc2, bl2, br2, xlb, xrb, DHID, DHID);
  gat_fused<DHID, 4, true, true, false, true><<<nwave_blocks, blk, 0, stream>>>(
      xlb, xrb, We2, at2, bo2, offs, csr_src, csr_ea, easum, g2, b2, hb, nullptr, actb1);

  // ---- layer 3 ----
  gemm_lr<<<dim3(2 * DOUT3 / 64, NN / 64), blk, 0, stream>>>(
      (const short*)actb1, (const short*)Wc3, bl3, br3, xlb, xrb, DHID, DOUT3);
  gat_fused<DOUT3, 1, false, false, true, false><<<nwave_blocks, blk, 0, stream>>>(
      xlb, xrb, We3, at3, bo3, offs, csr_src, csr_ea, easum, g3, b3, nullptr, h3, nullptr);

  // ---- pooling ----
  k_pool<<<NG, 128, 0, stream>>>(h3, bat, out);
}

// Round 10
// 274.468 us; speedup vs baseline: 2.2415x; 1.2087x over previous
//
#include <hip/hip_runtime.h>
#include <hip/hip_bf16.h>
#include <math.h>

#define NN 16384     // nodes
#define NE 262144    // edges
#define KDIM1 480
#define DHID 256
#define DOUT3 128
#define NG 256       // graphs

typedef short bf16x8 __attribute__((ext_vector_type(8)));
typedef float f32x4 __attribute__((ext_vector_type(4)));

#define LOG2E 1.44269504088896340736f

__device__ __forceinline__ unsigned short f2bf(float f) {
  unsigned u = __float_as_uint(f);
  unsigned r = (u + 0x7fffu + ((u >> 16) & 1u)) >> 16;
  return (unsigned short)r;
}
__device__ __forceinline__ float bf2f(unsigned short u) {
  return __uint_as_float((unsigned)u << 16);
}

__device__ __forceinline__ void gload_lds16(const void* g, void* l) {
  __builtin_amdgcn_global_load_lds((const __attribute__((address_space(1))) void*)g,
                                   (__attribute__((address_space(3))) void*)l,
                                   16, 0, 0);
}

// ============================ CSR build ============================

__global__ __launch_bounds__(256) void k_edge_count(const int* __restrict__ ei,
                                                    const float* __restrict__ ea,
                                                    int* __restrict__ deg,
                                                    float* __restrict__ easum) {
  int e = blockIdx.x * 256 + threadIdx.x;
  if (e >= NE) return;
  int d = ei[NE + e];
  atomicAdd(&deg[d], 1);
  atomicAdd(&easum[d], ea[e]);
}

__global__ __launch_bounds__(1024) void k_scan(const int* __restrict__ deg,
                                               float* __restrict__ easum,
                                               int* __restrict__ offs,
                                               int* __restrict__ cursor) {
  __shared__ int sums[1024];
  int t = threadIdx.x;
  int base = t * 16;
  int local[16];
  int s = 0;
#pragma unroll
  for (int i = 0; i < 16; ++i) { local[i] = deg[base + i]; s += local[i]; }
  sums[t] = s;
  __syncthreads();
  for (int d = 1; d < 1024; d <<= 1) {
    int v = (t >= d) ? sums[t - d] : 0;
    __syncthreads();
    sums[t] += v;
    __syncthreads();
  }
  int prefix = (t == 0) ? 0 : sums[t - 1];
#pragma unroll
  for (int i = 0; i < 16; ++i) {
    offs[base + i] = prefix;
    cursor[base + i] = prefix;
    prefix += local[i];
  }
  if (t == 1023) offs[NN] = prefix;
#pragma unroll
  for (int i = 0; i < 16; ++i) {
    easum[base + i] = easum[base + i] / fmaxf((float)local[i], 1.f);
  }
}

__global__ __launch_bounds__(256) void k_fill_csr(const int* __restrict__ ei,
                                                  const float* __restrict__ ea,
                                                  int* __restrict__ cursor,
                                                  int* __restrict__ csr_src,
                                                  float* __restrict__ csr_ea) {
  int e = blockIdx.x * 256 + threadIdx.x;
  if (e >= NE) return;
  int s = ei[e];
  int d = ei[NE + e];
  int pos = atomicAdd(&cursor[d], 1);
  csr_src[pos] = s;
  csr_ea[pos] = ea[e];
}

// ============================ conversions ============================

__global__ __launch_bounds__(256) void k_f32_to_bf16(const float* __restrict__ in,
                                                     unsigned short* __restrict__ out,
                                                     int n) {
  int i = (blockIdx.x * 256 + threadIdx.x) * 4;
  if (i >= n) return;
  float4 v = *(const float4*)&in[i];
  ushort4 o;
  o.x = f2bf(v.x); o.y = f2bf(v.y); o.z = f2bf(v.z); o.w = f2bf(v.w);
  *(ushort4*)&out[i] = o;
}

// Wt[n][k] = bf16(W[k][n])
__global__ __launch_bounds__(256) void k_transpose_bf16(const float* __restrict__ W,
                                                        unsigned short* __restrict__ Wt,
                                                        int K, int N) {
  int idx = blockIdx.x * 256 + threadIdx.x;
  if (idx >= K * N) return;
  int n = idx / K, k = idx % K;
  Wt[idx] = f2bf(W[(size_t)k * N + n]);
}

// Wt[n][k], n in [0,2*NH): n<NH -> Wl[k][n], else Wr[k][n-NH]
__global__ __launch_bounds__(256) void k_transpose_lr(const float* __restrict__ Wl,
                                                      const float* __restrict__ Wr,
                                                      unsigned short* __restrict__ Wt,
                                                      int K, int NH) {
  int idx = blockIdx.x * 256 + threadIdx.x;
  if (idx >= 2 * NH * K) return;
  int n = idx / K, k = idx % K;
  float v = (n < NH) ? Wl[(size_t)k * NH + n] : Wr[(size_t)k * NH + (n - NH)];
  Wt[idx] = f2bf(v);
}

// ============================ bf16 MFMA GEMM cores ============================
// Shared main loop: 64x64 tile, BK=32, 4 waves (2x2), wave tile 32x32.

#define GEMM_CORE(A_, Bt_, K_)                                                   \
  __shared__ short As[64 * 32];                                                  \
  __shared__ short Bs[64 * 32];                                                  \
  int t = threadIdx.x;                                                           \
  int w = t >> 6;                                                                \
  int lane = t & 63;                                                             \
  int bm = blockIdx.y * 64;                                                      \
  int bn = blockIdx.x * 64;                                                      \
  int wr = w >> 1, wc = w & 1;                                                   \
  const short* Ag = A_ + (size_t)(bm + w * 16 + (lane >> 2)) * K_ + (lane & 3) * 8; \
  const short* Bg = Bt_ + (size_t)(bn + w * 16 + (lane >> 2)) * K_ + (lane & 3) * 8; \
  short* Al = &As[w * 16 * 32];                                                  \
  short* Bl = &Bs[w * 16 * 32];                                                  \
  f32x4 acc[2][2] = {};                                                          \
  int ar0 = (wr * 32 + (lane & 15)) * 32 + (lane >> 4) * 8;                      \
  int br0 = (wc * 32 + (lane & 15)) * 32 + (lane >> 4) * 8;                      \
  for (int k0 = 0; k0 < K_; k0 += 32) {                                          \
    gload_lds16(Ag, Al);                                                         \
    gload_lds16(Bg, Bl);                                                         \
    Ag += 32; Bg += 32;                                                          \
    __syncthreads();                                                             \
    bf16x8 a0 = *(const bf16x8*)&As[ar0];                                        \
    bf16x8 a1 = *(const bf16x8*)&As[ar0 + 16 * 32];                              \
    bf16x8 b0 = *(const bf16x8*)&Bs[br0];                                        \
    bf16x8 b1 = *(const bf16x8*)&Bs[br0 + 16 * 32];                              \
    acc[0][0] = __builtin_amdgcn_mfma_f32_16x16x32_bf16(a0, b0, acc[0][0], 0, 0, 0); \
    acc[0][1] = __builtin_amdgcn_mfma_f32_16x16x32_bf16(a0, b1, acc[0][1], 0, 0, 0); \
    acc[1][0] = __builtin_amdgcn_mfma_f32_16x16x32_bf16(a1, b0, acc[1][0], 0, 0, 0); \
    acc[1][1] = __builtin_amdgcn_mfma_f32_16x16x32_bf16(a1, b1, acc[1][1], 0, 0, 0); \
    __syncthreads();                                                             \
  }                                                                              \
  int col = lane & 15;                                                           \
  int row4 = (lane >> 4) * 4;

// C left/right split, bf16 outputs. grid.x = 2*NH/64.
__global__ __launch_bounds__(256) void gemm_lr(const short* __restrict__ A,
                                               const short* __restrict__ Wt,
                                               const float* __restrict__ bl,
                                               const float* __restrict__ br,
                                               unsigned short* __restrict__ xlb,
                                               unsigned short* __restrict__ xrb,
                                               int K, int NH) {
  GEMM_CORE(A, Wt, K)
  bool right = (bn >= NH);
  unsigned short* outp = right ? xrb : xlb;
  const float* bias = right ? br : bl;
  int cbase = right ? bn - NH : bn;
#pragma unroll
  for (int mi = 0; mi < 2; ++mi) {
#pragma unroll
    for (int ni = 0; ni < 2; ++ni) {
      f32x4 a = acc[mi][ni];
      int gc = cbase + wc * 32 + ni * 16 + col;
      float bv = bias[gc];
#pragma unroll
      for (int r = 0; r < 4; ++r) {
        int gr = bm + wr * 32 + mi * 16 + row4 + r;
        outp[(size_t)gr * NH + gc] = f2bf(a[r] + bv);
      }
    }
  }
}

// Cf += A@Wt (f32); outb = bf16(result). For the Wres residual GEMM.
__global__ __launch_bounds__(256) void gemm_res(const short* __restrict__ A,
                                                const short* __restrict__ Wt,
                                                float* __restrict__ Cf,
                                                unsigned short* __restrict__ outb,
                                                int K, int N) {
  GEMM_CORE(A, Wt, K)
#pragma unroll
  for (int mi = 0; mi < 2; ++mi) {
#pragma unroll
    for (int ni = 0; ni < 2; ++ni) {
      f32x4 a = acc[mi][ni];
      int gc = bn + wc * 32 + ni * 16 + col;
#pragma unroll
      for (int r = 0; r < 4; ++r) {
        int gr = bm + wr * 32 + mi * 16 + row4 + r;
        size_t o = (size_t)gr * N + gc;
        float v = a[r] + Cf[o];
        Cf[o] = v;
        outb[o] = f2bf(v);
      }
    }
  }
}

// ============================ fused GATv2 + LN (+GELU) (+RES) ============================
// One wave per node; bf16 gather; online softmax in exp2 domain; edge loop
// unrolled x2 with merged rescale; CSR loads scalarized via readfirstlane.

template<int D, int H, bool GELU_, bool RES_, bool WF32, bool WBF16>
__global__ __launch_bounds__(256) void gat_fused(
    const unsigned short* __restrict__ xlb, const unsigned short* __restrict__ xrb,
    const float* __restrict__ We, const float* __restrict__ att,
    const float* __restrict__ bo,
    const int* __restrict__ offs, const int* __restrict__ csr_src,
    const float* __restrict__ csr_ea, const float* __restrict__ loop_ea,
    const float* __restrict__ g, const float* __restrict__ bln,
    const float* __restrict__ res,
    float* __restrict__ outf, unsigned short* __restrict__ outb) {
  constexpr int P = D / 64;
  constexpr int C = D / H;
  constexpr int GROUP = C / P;   // lanes per head
  int n = (blockIdx.x * blockDim.x + threadIdx.x) >> 6;
  int lane = threadIdx.x & 63;
  if (n >= NN) return;
  int d0 = lane * P;

  float xrv[P], wev[P], attv[P];
  if constexpr (P == 4) {
    ushort4 u = *(const ushort4*)&xrb[(size_t)n * D + d0];
    xrv[0] = bf2f(u.x); xrv[1] = bf2f(u.y); xrv[2] = bf2f(u.z); xrv[3] = bf2f(u.w);
    *(float4*)wev = *(const float4*)&We[d0];
    *(float4*)attv = *(const float4*)&att[d0];
  } else {
    ushort2 u = *(const ushort2*)&xrb[(size_t)n * D + d0];
    xrv[0] = bf2f(u.x); xrv[1] = bf2f(u.y);
    *(float2*)wev = *(const float2*)&We[d0];
    *(float2*)attv = *(const float2*)&att[d0];
  }
#pragma unroll
  for (int p = 0; p < P; ++p) attv[p] *= LOG2E;   // exp2 domain (monotone)

#define GATHER(dst, srcidx)                                                  \
  {                                                                          \
    if constexpr (P == 4) {                                                  \
      ushort4 u_ = *(const ushort4*)&xlb[(size_t)(srcidx) * D + d0];         \
      dst[0] = bf2f(u_.x); dst[1] = bf2f(u_.y);                              \
      dst[2] = bf2f(u_.z); dst[3] = bf2f(u_.w);                              \
    } else {                                                                 \
      ushort2 u_ = *(const ushort2*)&xlb[(size_t)(srcidx) * D + d0];         \
      dst[0] = bf2f(u_.x); dst[1] = bf2f(u_.y);                              \
    }                                                                        \
  }

#define ALPHA(out_, xv_, eav_)                                               \
  {                                                                          \
    float partial_ = 0.f;                                                    \
    _Pragma("unroll")                                                        \
    for (int p = 0; p < P; ++p) {                                            \
      float s_ = xv_[p] + xrv[p] + (eav_) * wev[p];                          \
      s_ = fmaxf(s_, 0.2f * s_);                                             \
      partial_ = fmaf(s_, attv[p], partial_);                                \
    }                                                                        \
    _Pragma("unroll")                                                        \
    for (int w_ = 1; w_ < GROUP; w_ <<= 1) partial_ += __shfl_xor(partial_, w_, 64); \
    out_ = partial_;                                                         \
  }

  // ---- self-loop prologue: m = alpha_self, l = 1, acc = xv_self ----
  float acc[P];
  float xs[P];
  GATHER(xs, n)
  float m;
  ALPHA(m, xs, loop_ea[n])
  float l = 1.f;
#pragma unroll
  for (int p = 0; p < P; ++p) acc[p] = xs[p];

  int beg = offs[n];
  int cnt = offs[n + 1] - beg;
  int sbeg = __builtin_amdgcn_readfirstlane(beg);
  int scnt = __builtin_amdgcn_readfirstlane(cnt);

  int e = 0;
  for (; e + 2 <= scnt; e += 2) {
    int src0 = csr_src[sbeg + e];
    int src1 = csr_src[sbeg + e + 1];
    float ea0 = csr_ea[sbeg + e];
    float ea1 = csr_ea[sbeg + e + 1];
    float xv0[P], xv1[P];
    GATHER(xv0, src0)
    GATHER(xv1, src1)
    float a0, a1;
    ALPHA(a0, xv0, ea0)
    ALPHA(a1, xv1, ea1)
    float nm = fmaxf(m, fmaxf(a0, a1));
    float sc = exp2f(m - nm);
    float pe0 = exp2f(a0 - nm);
    float pe1 = exp2f(a1 - nm);
    l = fmaf(l, sc, pe0 + pe1);
#pragma unroll
    for (int p = 0; p < P; ++p)
      acc[p] = fmaf(acc[p], sc, fmaf(pe0, xv0[p], pe1 * xv1[p]));
    m = nm;
  }
  if (e < scnt) {
    int src0 = csr_src[sbeg + e];
    float ea0 = csr_ea[sbeg + e];
    float xv0[P];
    GATHER(xv0, src0)
    float a0;
    ALPHA(a0, xv0, ea0)
    float nm = fmaxf(m, a0);
    float sc = exp2f(m - nm);
    float pe0 = exp2f(a0 - nm);
    l = fmaf(l, sc, pe0);
#pragma unroll
    for (int p = 0; p < P; ++p) acc[p] = fmaf(acc[p], sc, pe0 * xv0[p]);
    m = nm;
  }
#undef GATHER
#undef ALPHA

  float inv = 1.f / l;
  float y[P];
#pragma unroll
  for (int p = 0; p < P; ++p) y[p] = fmaf(acc[p], inv, bo[d0 + p]);

  // fused LayerNorm over the wave-held row
  float s = 0.f, s2 = 0.f;
#pragma unroll
  for (int p = 0; p < P; ++p) { s += y[p]; s2 = fmaf(y[p], y[p], s2); }
#pragma unroll
  for (int w = 1; w < 64; w <<= 1) {
    s += __shfl_xor(s, w, 64);
    s2 += __shfl_xor(s2, w, 64);
  }
  float mu = s * (1.f / D);
  float var = s2 * (1.f / D) - mu * mu;
  float rr = rsqrtf(var + 1e-5f);

  float z[P];
#pragma unroll
  for (int p = 0; p < P; ++p) {
    float v = (y[p] - mu) * rr * g[d0 + p] + bln[d0 + p];
    if (GELU_) v = 0.5f * v * (1.f + erff(v * 0.70710678118654752f));
    if (RES_) v += res[(size_t)n * D + d0 + p];
    z[p] = v;
  }
  if (WF32) {
    float* orow = outf + (size_t)n * D;
    if constexpr (P == 4) *(float4*)&orow[d0] = *(float4*)z;
    else                  *(float2*)&orow[d0] = *(float2*)z;
  }
  if (WBF16) {
    unsigned short* orow = outb + (size_t)n * D;
    if constexpr (P == 4) {
      ushort4 o; o.x = f2bf(z[0]); o.y = f2bf(z[1]); o.z = f2bf(z[2]); o.w = f2bf(z[3]);
      *(ushort4*)&orow[d0] = o;
    } else {
      ushort2 o; o.x = f2bf(z[0]); o.y = f2bf(z[1]);
      *(ushort2*)&orow[d0] = o;
    }
  }
}

// ============================ pooling ============================

__device__ __forceinline__ int lower_bound_i(const int* arr, int n, int val) {
  int lo = 0, hi = n;
  while (lo < hi) {
    int mid = (lo + hi) >> 1;
    if (arr[mid] < val) lo = mid + 1; else hi = mid;
  }
  return lo;
}

__global__ __launch_bounds__(128) void k_pool(const float* __restrict__ h3,
                                              const int* __restrict__ batch,
                                              float* __restrict__ out) {
  int gidx = blockIdx.x;
  int d = threadIdx.x;
  int lo = lower_bound_i(batch, NN, gidx);
  int hi = lower_bound_i(batch, NN, gidx + 1);
  float s = 0.f;
  for (int n = lo; n < hi; ++n) s += h3[(size_t)n * DOUT3 + d];
  int cnt = hi - lo;
  out[gidx * DOUT3 + d] = s / fmaxf((float)cnt, 1.f);
}

// ============================ launch ============================

extern "C" void kernel_launch(void* const* d_in, const int* in_sizes, int n_in,
                              void* d_out, int out_size, void* d_ws, size_t ws_size,
                              hipStream_t stream) {
  const float* x   = (const float*)d_in[0];
  const int*   ei  = (const int*)d_in[1];
  const float* ea  = (const float*)d_in[2];
  const int*   bat = (const int*)d_in[3];
  // d_in[4] = num_graphs (256, hardcoded)
  const float* Wl1 = (const float*)d_in[5];  const float* bl1 = (const float*)d_in[6];
  const float* Wr1 = (const float*)d_in[7];  const float* br1 = (const float*)d_in[8];
  const float* We1 = (const float*)d_in[9];  const float* at1 = (const float*)d_in[10];
  const float* bo1 = (const float*)d_in[11];
  const float* Wl2 = (const float*)d_in[12]; const float* bl2 = (const float*)d_in[13];
  const float* Wr2 = (const float*)d_in[14]; const float* br2 = (const float*)d_in[15];
  const float* We2 = (const float*)d_in[16]; const float* at2 = (const float*)d_in[17];
  const float* bo2 = (const float*)d_in[18];
  const float* Wl3 = (const float*)d_in[19]; const float* bl3 = (const float*)d_in[20];
  const float* Wr3 = (const float*)d_in[21]; const float* br3 = (const float*)d_in[22];
  const float* We3 = (const float*)d_in[23]; const float* at3 = (const float*)d_in[24];
  const float* bo3 = (const float*)d_in[25];
  const float* g1 = (const float*)d_in[26]; const float* b1 = (const float*)d_in[27];
  const float* g2 = (const float*)d_in[28]; const float* b2 = (const float*)d_in[29];
  const float* g3 = (const float*)d_in[30]; const float* b3 = (const float*)d_in[31];
  const float* Wres = (const float*)d_in[32];
  float* out = (float*)d_out;

  char* ws = (char*)d_ws;
  size_t off = 0;
  unsigned short* xlb = (unsigned short*)(ws + off); off += (size_t)NN * DHID * 2;
  unsigned short* xrb = (unsigned short*)(ws + off); off += (size_t)NN * DHID * 2;
  float* hb = (float*)(ws + off); off += (size_t)NN * DHID * 4;
  float* h3 = (float*)(ws + off); off += (size_t)NN * DOUT3 * 4;
  unsigned short* actb0 = (unsigned short*)(ws + off); off += (size_t)NN * KDIM1 * 2;
  unsigned short* actb1 = (unsigned short*)(ws + off); off += (size_t)NN * DHID * 2;
  int*   deg    = (int*)(ws + off); off += NN * 4;
  int*   offs   = (int*)(ws + off); off += (NN + 1) * 4 + 60;
  int*   cursor = (int*)(ws + off); off += NN * 4;
  float* easum  = (float*)(ws + off); off += NN * 4;
  int*   csr_src = (int*)(ws + off); off += (size_t)NE * 4;
  float* csr_ea  = (float*)(ws + off); off += (size_t)NE * 4;
  unsigned short* Wc1 = (unsigned short*)(ws + off); off += (size_t)2 * DHID * KDIM1 * 2;
  unsigned short* Wrs = (unsigned short*)(ws + off); off += (size_t)DHID * KDIM1 * 2;
  unsigned short* Wc2 = (unsigned short*)(ws + off); off += (size_t)2 * DHID * DHID * 2;
  unsigned short* Wc3 = (unsigned short*)(ws + off); off += (size_t)2 * DOUT3 * DHID * 2;

  // ---- CSR build + conversions ----
  hipMemsetAsync(deg, 0, NN * 4, stream);
  hipMemsetAsync(easum, 0, NN * 4, stream);
  k_edge_count<<<NE / 256, 256, 0, stream>>>(ei, ea, deg, easum);
  k_scan<<<1, 1024, 0, stream>>>(deg, easum, offs, cursor);
  k_fill_csr<<<NE / 256, 256, 0, stream>>>(ei, ea, cursor, csr_src, csr_ea);

  k_f32_to_bf16<<<(NN * KDIM1 / 4 + 255) / 256, 256, 0, stream>>>(x, actb0, NN * KDIM1);
  k_transpose_lr<<<(2 * DHID * KDIM1 + 255) / 256, 256, 0, stream>>>(Wl1, Wr1, Wc1, KDIM1, DHID);
  k_transpose_bf16<<<(DHID * KDIM1 + 255) / 256, 256, 0, stream>>>(Wres, Wrs, KDIM1, DHID);
  k_transpose_lr<<<(2 * DHID * DHID + 255) / 256, 256, 0, stream>>>(Wl2, Wr2, Wc2, DHID, DHID);
  k_transpose_lr<<<(2 * DOUT3 * DHID + 255) / 256, 256, 0, stream>>>(Wl3, Wr3, Wc3, DHID, DOUT3);

  dim3 blk(256);
  int nwave_blocks = NN / 4;

  // ---- layer 1 ----
  gemm_lr<<<dim3(2 * DHID / 64, NN / 64), blk, 0, stream>>>(
      (const short*)actb0, (const short*)Wc1, bl1, br1, xlb, xrb, KDIM1, DHID);
  gat_fused<DHID, 4, true, false, true, false><<<nwave_blocks, blk, 0, stream>>>(
      xlb, xrb, We1, at1, bo1, offs, csr_src, csr_ea, easum, g1, b1, nullptr, hb, nullptr);
  gemm_res<<<dim3(DHID / 64, NN / 64), blk, 0, stream>>>(
      (const short*)actb0, (const short*)Wrs, hb, actb1, KDIM1, DHID);

  // ---- layer 2 ----
  gemm_lr<<<dim3(2 * DHID / 64, NN / 64), blk, 0, stream>>>(
      (const short*)actb1, (const short*)Wc2, bl2, br2, xlb, xrb, DHID, DHID);
  gat_fused<DHID, 4, true, true, false, true><<<nwave_blocks, blk, 0, stream>>>(
      xlb, xrb, We2, at2, bo2, offs, csr_src, csr_ea, easum, g2, b2, hb, nullptr, actb1);

  // ---- layer 3 ----
  gemm_lr<<<dim3(2 * DOUT3 / 64, NN / 64), blk, 0, stream>>>(
      (const short*)actb1, (const short*)Wc3, bl3, br3, xlb, xrb, DHID, DOUT3);
  gat_fused<DOUT3, 1, false, false, true, false><<<nwave_blocks, blk, 0, stream>>>(
      xlb, xrb, We3, at3, bo3, offs, csr_src, csr_ea, easum, g3, b3, nullptr, h3, nullptr);

  // ---- pooling ----
  k_pool<<<NG, 128, 0, stream>>>(h3, bat, out);
}